// Round 1
// baseline (180.972 us; speedup 1.0000x reference)
//
#include <hip/hip_runtime.h>

#define MAX_REL 16
#define NTAB    33          // 2*MAX_REL+1
#define B       4
#define H       8
#define LQ      1024
#define DH      64
#define KLEN    1024
#define QTILE   16          // q rows per block in pe_kernel

// Kernel 1: proj[row][j] = dot(query[row, :], rel_table[j, :])
// row = (b*H + h)*LQ + q, 32768 rows, 33 table entries -> 1,081,344 tasks.
__global__ __launch_bounds__(256) void proj_kernel(const float* __restrict__ query,
                                                   const float* __restrict__ table,
                                                   float* __restrict__ proj) {
    int task = blockIdx.x * 256 + threadIdx.x;
    const int NROWS = B * H * LQ;
    if (task >= NROWS * NTAB) return;
    int row = task / NTAB;          // magic-mul div
    int j   = task - row * NTAB;
    const float4* qv = (const float4*)(query + (size_t)row * DH);
    const float4* tv = (const float4*)(table + (size_t)j * DH);
    float acc = 0.f;
#pragma unroll
    for (int i = 0; i < DH / 4; ++i) {
        float4 a = qv[i];
        float4 t = tv[i];
        acc += a.x * t.x + a.y * t.y + a.z * t.z + a.w * t.w;
    }
    proj[task] = acc;
}

// Kernel 2: out[row][k] = proj[row][clip(ts[b,k]-ts[b,q],-16,16)+16]
// One block handles (b, h, 16 q-rows). 256 threads x float4 stores per row.
__global__ __launch_bounds__(256) void pe_kernel(const int* __restrict__ time_ids,
                                                 const float* __restrict__ proj,
                                                 float* __restrict__ out) {
    __shared__ int   ts[KLEN];
    __shared__ float pr[QTILE * NTAB];   // 528 floats

    const int tid  = threadIdx.x;
    const int tile = blockIdx.x;         // 0 .. B*H*(LQ/QTILE)-1
    const int bh   = tile >> 6;          // LQ/QTILE = 64 tiles per (b,h)
    const int qt   = tile & 63;
    const int b    = bh >> 3;            // H = 8
    const int q0   = qt * QTILE;

    // stage ts[b, 0..1023] : 256 threads x int4
    ((int4*)ts)[tid] = ((const int4*)(time_ids + b * KLEN))[tid];

    // stage proj for this tile's 16 rows (contiguous 528 floats)
    const int rowbase = bh * LQ + q0;
    const float* pg = proj + (size_t)rowbase * NTAB;
    for (int i = tid; i < QTILE * NTAB; i += 256) pr[i] = pg[i];
    __syncthreads();

    const int k0 = tid << 2;
    const int4 tk = ((const int4*)ts)[tid];
    float* op = out + (size_t)rowbase * KLEN + k0;

#pragma unroll
    for (int r = 0; r < QTILE; ++r) {
        const int tq = ts[q0 + r];                    // LDS broadcast
        int i0 = min(max(tk.x - tq, -MAX_REL), MAX_REL) + MAX_REL;
        int i1 = min(max(tk.y - tq, -MAX_REL), MAX_REL) + MAX_REL;
        int i2 = min(max(tk.z - tq, -MAX_REL), MAX_REL) + MAX_REL;
        int i3 = min(max(tk.w - tq, -MAX_REL), MAX_REL) + MAX_REL;
        const float* prr = pr + r * NTAB;
        float4 v = make_float4(prr[i0], prr[i1], prr[i2], prr[i3]);
        *((float4*)op) = v;
        op += KLEN;
    }
}

extern "C" void kernel_launch(void* const* d_in, const int* in_sizes, int n_in,
                              void* d_out, int out_size, void* d_ws, size_t ws_size,
                              hipStream_t stream) {
    const float* query    = (const float*)d_in[0];   // (B,H,LQ,DH) f32
    const float* table    = (const float*)d_in[1];   // (33, DH) f32
    const int*   time_ids = (const int*)d_in[2];     // (B, KLEN) int32
    // d_in[3] = k_len scalar (fixed 1024; shapes hardcoded from setup_inputs)
    float* proj = (float*)d_ws;                      // 32768*33 f32 = 4.32 MB
    float* out  = (float*)d_out;                     // (B,H,LQ,KLEN) f32

    const int ntasks = B * H * LQ * NTAB;            // 1,081,344
    proj_kernel<<<(ntasks + 255) / 256, 256, 0, stream>>>(query, table, proj);
    pe_kernel<<<B * H * (LQ / QTILE), 256, 0, stream>>>(time_ids, proj, out);
}

// Round 2
// 149.733 us; speedup vs baseline: 1.2086x; 1.2086x over previous
//
#include <hip/hip_runtime.h>

#define MAX_REL 16
#define NTAB    33          // 2*MAX_REL+1
#define B       4
#define H       8
#define LQ      1024
#define DH      64
#define KLEN    1024
#define QTILE   16          // q rows per block
#define TSTRIDE 68          // padded table row stride (floats); 68*4=272 B, 16-B aligned, breaks bank aliasing

// One block = (b, h, 16 q-rows). Phase 1: stage ts + query tile + table into LDS.
// Phase 2: proj[r][j] = dot(q_row[r], table[j]) for the 16x33 tile.
// Phase 3: out[row][k] = proj[r][clip(ts[k]-ts[q],-16,16)+16], float4 stores.
__global__ __launch_bounds__(256) void fused_pe_kernel(const float* __restrict__ query,
                                                       const float* __restrict__ table,
                                                       const int* __restrict__ time_ids,
                                                       float* __restrict__ out) {
    __shared__ int   ts[KLEN];                 // 4 KB
    __shared__ float qt[QTILE * DH];           // 4 KB
    __shared__ float tb[NTAB * TSTRIDE];       // 8.8 KB
    __shared__ float pr[QTILE * NTAB];         // 2.1 KB

    const int tid  = threadIdx.x;
    const int tile = blockIdx.x;               // 0 .. B*H*64-1
    const int bh   = tile >> 6;                // 64 tiles per (b,h)
    const int qt_i = tile & 63;
    const int b    = bh >> 3;                  // H = 8
    const int q0   = qt_i * QTILE;
    const int rowbase = bh * LQ + q0;

    // ---- Phase 1: staging ----
    ((int4*)ts)[tid] = ((const int4*)(time_ids + b * KLEN))[tid];          // 4 KB
    ((float4*)qt)[tid] = ((const float4*)(query + (size_t)rowbase * DH))[tid]; // 16 rows x 64
    // table: 33 rows x 16 float4, into padded stride-68 rows
    for (int i = tid; i < NTAB * 16; i += 256) {
        int r = i >> 4, c = i & 15;
        ((float4*)(tb + r * TSTRIDE))[c] = ((const float4*)(table + r * DH))[c];
    }
    __syncthreads();

    // ---- Phase 2: 528 dot products ----
    for (int t = tid; t < QTILE * NTAB; t += 256) {
        int r = t / NTAB;                      // const divisor -> magic mul
        int j = t - r * NTAB;
        const float4* qv = (const float4*)(qt + r * DH);   // broadcast across 33 lanes
        const float4* tv = (const float4*)(tb + j * TSTRIDE);
        float acc = 0.f;
#pragma unroll
        for (int i = 0; i < DH / 4; ++i) {
            float4 a = qv[i];
            float4 w = tv[i];
            acc += a.x * w.x + a.y * w.y + a.z * w.z + a.w * w.w;
        }
        pr[t] = acc;
    }
    __syncthreads();

    // ---- Phase 3: gather + coalesced float4 stores ----
    const int k0 = tid << 2;
    const int4 tk = ((const int4*)ts)[tid];
    float* op = out + (size_t)rowbase * KLEN + k0;

#pragma unroll
    for (int r = 0; r < QTILE; ++r) {
        const int tq = ts[q0 + r];             // LDS broadcast
        int i0 = min(max(tk.x - tq, -MAX_REL), MAX_REL) + MAX_REL;
        int i1 = min(max(tk.y - tq, -MAX_REL), MAX_REL) + MAX_REL;
        int i2 = min(max(tk.z - tq, -MAX_REL), MAX_REL) + MAX_REL;
        int i3 = min(max(tk.w - tq, -MAX_REL), MAX_REL) + MAX_REL;
        const float* prr = pr + r * NTAB;
        float4 v = make_float4(prr[i0], prr[i1], prr[i2], prr[i3]);
        *((float4*)op) = v;
        op += KLEN;
    }
}

extern "C" void kernel_launch(void* const* d_in, const int* in_sizes, int n_in,
                              void* d_out, int out_size, void* d_ws, size_t ws_size,
                              hipStream_t stream) {
    const float* query    = (const float*)d_in[0];   // (B,H,LQ,DH) f32
    const float* table    = (const float*)d_in[1];   // (33, DH) f32
    const int*   time_ids = (const int*)d_in[2];     // (B, KLEN) int32
    float* out = (float*)d_out;                      // (B,H,LQ,KLEN) f32

    fused_pe_kernel<<<B * H * (LQ / QTILE), 256, 0, stream>>>(query, table, time_ids, out);
}